// Round 10
// baseline (577.758 us; speedup 1.0000x reference)
//
#include <hip/hip_runtime.h>
#include <math.h>

#define HW 4096
#define NPIX (HW * HW)        // 16777216
#define N4 (NPIX / 4)         // 4194304
#define TS 32
#define MED_RANK 8388607u     // floor(0.5*(N-1)), method='lower'
#define NOBIN 0xFFFFFFFFu
#define H1_COPIES 16
#define H23_COPIES 4
#define NSTRIPE 64

typedef unsigned int u32;
typedef unsigned long long u64;

__device__ __forceinline__ u32 f2key(float f) {
  u32 u = __float_as_uint(f);
  return (u & 0x80000000u) ? ~u : (u | 0x80000000u);
}

// Wave-aggregated LDS histogram add: one atomic per same-bin run across the
// wave (R is spatially smooth -> long runs). Requires ALL 64 lanes active.
__device__ __forceinline__ void wave_hist_add(u32* lh, u32 bin) {
  int lane = threadIdx.x & 63;
  u32 prev = __shfl_up(bin, 1);
  bool head = (lane == 0) || (prev != bin);
  u64 hb = __ballot(head);
  u64 after = (lane < 63) ? (hb >> (lane + 1)) : 0ull;
  int run = after ? __ffsll((long long)after) : (64 - lane);
  if (head && bin != NOBIN) atomicAdd(&lh[bin], (u32)run);
}

// ---------------------------------------------------------------------------
// Fused Sobel -> products -> separable 9x9 Gaussian -> Harris R.
// POOL=false: RT=32, write R tile + fused 1024-bin (top-10-bit) histogram
//             (merged into one of H1_COPIES striped global copies).
// POOL=true (fallback, no ws for R): RT=38 w/ halo 3, threshold+7x7 NMS.
// ---------------------------------------------------------------------------
template <int RT, bool POOL>
__global__ __launch_bounds__(256, 4) void harris_main(
    const float* __restrict__ x, const float* __restrict__ gw,
    const u32* __restrict__ sel, float* __restrict__ Rout,
    u32* __restrict__ h1) {
  constexpr int PR = RT + 8;            // products region (Gauss halo 4)
  constexpr int XR = RT + 10;           // input region (+ Sobel halo 1)
  constexpr int CGR = (RT + 3) / 4;     // 4-wide col groups
  constexpr int VP = ((((CGR - 1) * 4 + 12) + 3) / 4) * 4 + 4;  // v stride,
  // padded to 44 (RT=32): bank starts 12r mod 32 -> uniform 8 dwords/bank
  constexpr int RTD = POOL ? RT : 1;
  constexpr int NH = POOL ? 1 : 1024;
  constexpr int XIN_F = XR * (XR + 2);
  constexpr int V_F = 3 * RT * VP;
  constexpr int UNI_F = (XIN_F > V_F) ? XIN_F : V_F;

  // xin and v have disjoint lifetimes (barrier-separated) -> union them
  __shared__ __align__(16) float uni[UNI_F];
  __shared__ float p0[PR][PR], p1[PR][PR], p2[PR][PR];
  __shared__ float g1s[12];
  __shared__ float rt[RTD][RTD + 2];
  __shared__ float hm[RTD][TS];
  __shared__ u32 lh[NH];

  float(*xin)[XR + 2] = (float(*)[XR + 2])uni;  // [XR][XR+2]
  float(*v)[VP] = (float(*)[VP])uni;            // [3*RT][VP]

  const int tid = threadIdx.x;
  const int or0 = blockIdx.y * TS - (POOL ? 3 : 0);
  const int oc0 = blockIdx.x * TS - (POOL ? 3 : 0);
  const int xr0 = or0 - 5, xc0 = oc0 - 5;
  const bool inter =
      (xr0 >= 0) && (xc0 >= 0) && (xr0 + XR <= HW) && (xc0 + XR <= HW);

  if constexpr (!POOL)
    for (int i = tid; i < NH; i += 256) lh[i] = 0u;

  // 1D normalized gaussian taps = row sums of the normalized 2D kernel
  if (tid < 9) {
    float s = 0.f;
#pragma unroll
    for (int j = 0; j < 9; ++j) s += gw[tid * 9 + j];
    g1s[tid] = s;
  }

  // stage input tile (zero-padded); interior fast path skips guards
  if (inter) {
    for (int idx = tid; idx < XR * XR; idx += 256) {
      int r = idx / XR, c = idx % XR;
      xin[r][c] = x[(size_t)(xr0 + r) * HW + (xc0 + c)];
    }
  } else {
    for (int idx = tid; idx < XR * XR; idx += 256) {
      int r = idx / XR, c = idx % XR;
      int gr = xr0 + r, gc = xc0 + c;
      float val = 0.f;
      if ((u32)gr < (u32)HW && (u32)gc < (u32)HW) val = x[(size_t)gr * HW + gc];
      xin[r][c] = val;
    }
  }
  __syncthreads();

  // Sobel + products (zero outside image)
  if constexpr (!POOL) {
    // vectorized: 4 products/task via float4 LDS ops (PR=40 divisible by 4)
    for (int task = tid; task < PR * (PR / 4); task += 256) {
      int r = task / (PR / 4);
      int c4 = (task % (PR / 4)) * 4;
      __align__(16) float a[3][8];
#pragma unroll
      for (int rr = 0; rr < 3; ++rr) {
        *(float4*)&a[rr][0] = *(const float4*)&xin[r + rr][c4];
        *(float4*)&a[rr][4] = *(const float4*)&xin[r + rr][c4 + 4];
      }
      float4 P0, P1, P2;
      float* p0v = (float*)&P0;
      float* p1v = (float*)&P1;
      float* p2v = (float*)&P2;
      if (inter) {
#pragma unroll
        for (int o = 0; o < 4; ++o) {
          float Ix = (a[0][o + 2] - a[0][o]) + 2.f * (a[1][o + 2] - a[1][o]) +
                     (a[2][o + 2] - a[2][o]);
          float Iy = (a[2][o] - a[0][o]) + 2.f * (a[2][o + 1] - a[0][o + 1]) +
                     (a[2][o + 2] - a[0][o + 2]);
          p0v[o] = Ix * Ix;
          p1v[o] = Iy * Iy;
          p2v[o] = Ix * Iy;
        }
      } else {
        int gr = or0 - 4 + r;
        int gc0 = oc0 - 4 + c4;
#pragma unroll
        for (int o = 0; o < 4; ++o) {
          float Ix = (a[0][o + 2] - a[0][o]) + 2.f * (a[1][o + 2] - a[1][o]) +
                     (a[2][o + 2] - a[2][o]);
          float Iy = (a[2][o] - a[0][o]) + 2.f * (a[2][o + 1] - a[0][o + 1]) +
                     (a[2][o + 2] - a[0][o + 2]);
          bool in = ((u32)gr < (u32)HW) && ((u32)(gc0 + o) < (u32)HW);
          p0v[o] = in ? Ix * Ix : 0.f;
          p1v[o] = in ? Iy * Iy : 0.f;
          p2v[o] = in ? Ix * Iy : 0.f;
        }
      }
      *(float4*)&p0[r][c4] = P0;
      *(float4*)&p1[r][c4] = P1;
      *(float4*)&p2[r][c4] = P2;
    }
  } else {
    for (int idx = tid; idx < PR * PR; idx += 256) {
      int r = idx / PR, c = idx % PR;
      int gr = or0 - 4 + r, gc = oc0 - 4 + c;
      float P0 = 0.f, P1 = 0.f, P2 = 0.f;
      if ((u32)gr < (u32)HW && (u32)gc < (u32)HW) {
        float a00 = xin[r][c], a01 = xin[r][c + 1], a02 = xin[r][c + 2];
        float a10 = xin[r + 1][c], a12 = xin[r + 1][c + 2];
        float a20 = xin[r + 2][c], a21 = xin[r + 2][c + 1],
              a22 = xin[r + 2][c + 2];
        float Ix = (a02 - a00) + 2.f * (a12 - a10) + (a22 - a20);
        float Iy = (a20 - a00) + 2.f * (a21 - a01) + (a22 - a02);
        P0 = Ix * Ix;
        P1 = Iy * Iy;
        P2 = Ix * Iy;
      }
      p0[r][c] = P0;
      p1[r][c] = P1;
      p2[r][c] = P2;
    }
  }
  __syncthreads();  // also: last read of xin before v overwrites uni

  float g[9];
#pragma unroll
  for (int k = 0; k < 9; ++k) g[k] = g1s[k];

  // vertical 9-tap (writes v, overwriting xin region)
  if constexpr (!POOL) {
    // float4 across columns: 240 single-iteration tasks =
    // 3 ch x 8 row-groups(4) x 10 col-quads; 12 quad reads -> 4 quad writes
    if (tid < 240) {
      int ch = tid / 80;
      int rem = tid - ch * 80;
      int rg = (rem / 10) * 4;
      int c4 = (rem % 10) * 4;
      const float(*pp)[PR] = (ch == 0) ? p0 : (ch == 1) ? p1 : p2;
      float4 col[12];
#pragma unroll
      for (int k = 0; k < 12; ++k) col[k] = *(const float4*)&pp[rg + k][c4];
#pragma unroll
      for (int o = 0; o < 4; ++o) {
        float4 s = {0.f, 0.f, 0.f, 0.f};
#pragma unroll
        for (int k = 0; k < 9; ++k) {
          float4 cv = col[o + k];
          s.x = fmaf(g[k], cv.x, s.x);
          s.y = fmaf(g[k], cv.y, s.y);
          s.z = fmaf(g[k], cv.z, s.z);
          s.w = fmaf(g[k], cv.w, s.w);
        }
        *(float4*)&v[ch * RT + rg + o][c4] = s;
      }
    }
  } else {
    for (int task = tid; task < 3 * CGR * PR; task += 256) {
      int ch = task / (CGR * PR);
      int rem = task % (CGR * PR);
      int rg = (rem / PR) * 4;
      int c = rem % PR;
      const float(*pp)[PR] = (ch == 0) ? p0 : (ch == 1) ? p1 : p2;
      float col[12];
#pragma unroll
      for (int k = 0; k < 12; ++k) col[k] = (rg + k < PR) ? pp[rg + k][c] : 0.f;
#pragma unroll
      for (int o = 0; o < 4; ++o) {
        int rv = rg + o;
        if (rv < RT) {
          float s = 0.f;
#pragma unroll
          for (int k = 0; k < 9; ++k) s = fmaf(g[k], col[o + k], s);
          v[ch * RT + rv][c] = s;
        }
      }
    }
  }
  __syncthreads();

  float med = 0.f;
  if (POOL) med = __uint_as_float(sel[2]);

  // horizontal 9-tap + Harris R (4 cols/task, float4 LDS reads)
  for (int task = tid; task < RT * CGR; task += 256) {
    int r = task / CGR;
    int c0i = (task % CGR) * 4;
    float s3[3][4];
#pragma unroll
    for (int ch = 0; ch < 3; ++ch) {
      const float4* vp = (const float4*)&v[ch * RT + r][c0i];
      float4 w0 = vp[0], w1 = vp[1], w2 = vp[2];
      float row[12] = {w0.x, w0.y, w0.z, w0.w, w1.x, w1.y,
                       w1.z, w1.w, w2.x, w2.y, w2.z, w2.w};
#pragma unroll
      for (int o = 0; o < 4; ++o) {
        float s = 0.f;
#pragma unroll
        for (int k = 0; k < 9; ++k) s = fmaf(g[k], row[o + k], s);
        s3[ch][o] = s;
      }
    }
    if constexpr (!POOL) {
      float4 rv4;
      float* rp = (float*)&rv4;
#pragma unroll
      for (int o = 0; o < 4; ++o) {
        float Sxx = s3[0][o], Syy = s3[1][o], Sxy = s3[2][o];
        float tr = Sxx + Syy;
        rp[o] = Sxx * Syy - Sxy * Sxy - 0.05f * tr * tr;
      }
      *(float4*)&Rout[(size_t)(or0 + r) * HW + (oc0 + c0i)] = rv4;
      // fused pass-1 histogram (exactly 1 loop iteration: all lanes active)
#pragma unroll
      for (int o = 0; o < 4; ++o) wave_hist_add(lh, f2key(rp[o]) >> 22);
    } else {
#pragma unroll
      for (int o = 0; o < 4; ++o) {
        int c = c0i + o;
        if (c < RT) {
          float Sxx = s3[0][o], Syy = s3[1][o], Sxy = s3[2][o];
          float tr = Sxx + Syy;
          float Rv = Sxx * Syy - Sxy * Sxy - 0.05f * tr * tr;
          int gr = or0 + r, gc = oc0 + c;
          float val = -INFINITY;
          if ((u32)gr < (u32)HW && (u32)gc < (u32)HW)
            val = (Rv > med) ? Rv : 0.f;
          rt[r][c] = val;
        }
      }
    }
  }

  if constexpr (!POOL) {
    __syncthreads();
    // striped global merge: consecutive blocks hit different copies
    const u32 cp = (u32)(blockIdx.y * gridDim.x + blockIdx.x) & (H1_COPIES - 1);
    u32* dst = h1 + cp * NH;
    for (int i = tid; i < NH; i += 256) {
      u32 c = lh[i];
      if (c) atomicAdd(&dst[i], c);
    }
  }

  if constexpr (POOL) {
    __syncthreads();
    for (int idx = tid; idx < RT * TS; idx += 256) {
      int r = idx / TS, c = idx % TS;
      float m = rt[r][c];
#pragma unroll
      for (int k = 1; k < 7; ++k) m = fmaxf(m, rt[r][c + k]);
      hm[r][c] = m;
    }
    __syncthreads();
    for (int idx = tid; idx < TS * TS; idx += 256) {
      int r = idx / TS, c = idx % TS;
      float pooled = hm[r][c];
#pragma unroll
      for (int k = 1; k < 7; ++k) pooled = fmaxf(pooled, hm[r + k][c]);
      float rc = rt[r + 3][c + 3];
      Rout[(size_t)(or0 + 3 + r) * HW + (oc0 + 3 + c)] =
          (rc == pooled) ? rc : 0.f;
    }
  }
}

// ---------------------------------------------------------------------------
// Pass 2: 12-bit histogram of keys matching the 10-bit prefix + segmented
// compaction of matching keys (64 striped counters -> no same-address storm).
// ---------------------------------------------------------------------------
__global__ __launch_bounds__(256) void hist_pass2(
    const float4* __restrict__ R4, const u32* __restrict__ sel,
    u32* __restrict__ hist, u32* __restrict__ wcnt, u32* __restrict__ cbuf,
    u32 segcap) {
  __shared__ u32 lh[4096];
  for (int i = threadIdx.x; i < 4096; i += 256) lh[i] = 0u;
  const u32 p10 = sel[1] >> 22;
  __syncthreads();
  const int lane = threadIdx.x & 63;
  const u32 stripe = ((blockIdx.x << 2) + (threadIdx.x >> 6)) & (NSTRIPE - 1);
  u32* seg = cbuf + (size_t)stripe * segcap;
  const u32 stride = gridDim.x * 256;
  for (u32 i = blockIdx.x * 256 + threadIdx.x; i < N4; i += stride) {
    float4 f = R4[i];
    const float* fp = (const float*)&f;
    u32 k[4];
    bool mt[4];
#pragma unroll
    for (int j = 0; j < 4; ++j) {
      k[j] = f2key(fp[j]);
      mt[j] = (k[j] >> 22) == p10;
    }
#pragma unroll
    for (int j = 0; j < 4; ++j)
      wave_hist_add(lh, mt[j] ? ((k[j] >> 10) & 0xFFFu) : NOBIN);
    if (segcap) {
      // wave-aggregated segmented append
      u32 m = (u32)mt[0] + (u32)mt[1] + (u32)mt[2] + (u32)mt[3];
      u32 scan = m;
#pragma unroll
      for (int d = 1; d < 64; d <<= 1) {
        u32 t = __shfl_up(scan, d);
        if (lane >= d) scan += t;
      }
      u32 tot = __shfl(scan, 63);
      if (tot) {
        u32 base = 0;
        if (lane == 0) base = atomicAdd(&wcnt[stripe], tot);
        base = __shfl(base, 0);
        u32 pos = base + scan - m;
        u32 o1 = (u32)mt[0], o2 = o1 + (u32)mt[1], o3 = o2 + (u32)mt[2];
        if (mt[0] && pos < segcap) seg[pos] = k[0];
        if (mt[1] && pos + o1 < segcap) seg[pos + o1] = k[1];
        if (mt[2] && pos + o2 < segcap) seg[pos + o2] = k[2];
        if (mt[3] && pos + o3 < segcap) seg[pos + o3] = k[3];
      }
    }
  }
  __syncthreads();
  u32* dst = hist + (blockIdx.x & (H23_COPIES - 1)) * 4096;
  for (int i = threadIdx.x; i < 4096; i += 256) {
    u32 c = lh[i];
    if (c) atomicAdd(&dst[i], c);
  }
}

// ---------------------------------------------------------------------------
// Pass 3: 10-bit histogram of keys matching the 22-bit prefix.
// Uses the compacted segments when all fit; else full re-read of R.
// ---------------------------------------------------------------------------
__global__ __launch_bounds__(256) void hist_pass3(
    const float4* __restrict__ R4, const u32* __restrict__ sel,
    const u32* __restrict__ wcnt, const u32* __restrict__ cbuf, u32 segcap,
    u32* __restrict__ hist) {
  __shared__ u32 lh[1024];
  for (int i = threadIdx.x; i < 1024; i += 256) lh[i] = 0u;
  const u32 p22 = sel[1] >> 10;
  bool useC = (segcap > 0);
#pragma unroll 8
  for (int s = 0; s < NSTRIPE; ++s)
    if (wcnt[s] > segcap) useC = false;
  __syncthreads();
  if (useC) {
    // block b handles chunk (b>>6) of segment (b&63); padded loop keeps
    // all 64 lanes active for wave_hist_add
    const u32 s = blockIdx.x & (NSTRIPE - 1);
    const u32 chunk = blockIdx.x >> 6;  // 0..15
    const u32 n = wcnt[s];
    const u32 clen = (n + 15) >> 4;
    const u32 start = chunk * clen;
    const u32 end = (start + clen < n) ? (start + clen) : n;
    const u32* seg = cbuf + (size_t)s * segcap;
    if (start < end) {
      u32 span = end - start;
      u32 nit = (span + 255) >> 8;
      for (u32 it = 0; it < nit; ++it) {
        u32 i = start + it * 256 + threadIdx.x;
        u32 bin = NOBIN;
        if (i < end) {
          u32 k = seg[i];
          bin = ((k >> 10) == p22) ? (k & 0x3FFu) : NOBIN;
        }
        wave_hist_add(lh, bin);
      }
    }
  } else {
    const u32 stride = gridDim.x * 256;
    for (u32 i = blockIdx.x * 256 + threadIdx.x; i < N4; i += stride) {
      float4 f = R4[i];
      const float* fp = (const float*)&f;
#pragma unroll
      for (int j = 0; j < 4; ++j) {
        u32 k = f2key(fp[j]);
        if ((k >> 10) == p22) atomicAdd(&lh[k & 0x3FFu], 1u);
      }
    }
  }
  __syncthreads();
  u32* dst = hist + (blockIdx.x & (H23_COPIES - 1)) * 1024;
  for (int i = threadIdx.x; i < 1024; i += 256) {
    u32 c = lh[i];
    if (c) atomicAdd(&dst[i], c);
  }
}

// ---------------------------------------------------------------------------
// Serial rank-select within a striped histogram (sums NCOPY copies);
// updates (remaining rank, prefix); LAST also emits the median float bits.
// ---------------------------------------------------------------------------
template <int NBINS, int NCOPY, int SHIFT, bool FIRST, bool LAST>
__global__ __launch_bounds__(256) void scan_select(const u32* __restrict__ hist,
                                                   u32* __restrict__ sel) {
  __shared__ u32 part[256];
  constexpr int C = NBINS / 256;
  int tid = threadIdx.x;
  u32 s = 0;
  for (int i = 0; i < C; ++i) {
    u32 b = 0;
#pragma unroll
    for (int cp = 0; cp < NCOPY; ++cp) b += hist[cp * NBINS + tid * C + i];
    s += b;
  }
  part[tid] = s;
  __syncthreads();
  if (tid == 0) {
    u32 r = FIRST ? MED_RANK : sel[0];
    u32 cum = 0;
    int seg = 0;
    for (; seg < 255; ++seg) {
      u32 ps = part[seg];
      if (cum + ps > r) break;
      cum += ps;
    }
    int b = seg * C;
    for (int i = 0; i < C; ++i) {
      u32 h = 0;
#pragma unroll
      for (int cp = 0; cp < NCOPY; ++cp) h += hist[cp * NBINS + b];
      if (cum + h > r) break;
      cum += h;
      ++b;
    }
    sel[0] = r - cum;
    u32 pfx = (FIRST ? 0u : sel[1]) | ((u32)b << SHIFT);
    sel[1] = pfx;
    if (LAST)
      sel[2] = (pfx & 0x80000000u) ? (pfx ^ 0x80000000u) : ~pfx;
  }
}

// ---------------------------------------------------------------------------
// Threshold + 7x7 max-pool NMS from materialized R (plan A).
// float4 staging: rows r0..r0+37, cols c0-4..c0+35 (40 cols, 4-aligned).
// Needed window cols are local 1..38; cols 0,39 are alignment padding.
// ---------------------------------------------------------------------------
__global__ __launch_bounds__(256) void final_pool(const float* __restrict__ R,
                                                  const u32* __restrict__ sel,
                                                  float* __restrict__ out) {
  __shared__ __align__(16) float rt[38][44];
  __shared__ float hm[38][32];
  const float med = __uint_as_float(sel[2]);
  const int r0 = blockIdx.y * TS - 3;
  const int c0 = blockIdx.x * TS;
  const int c0m4 = c0 - 4;
  // stage + threshold (float4)
  for (int idx = threadIdx.x; idx < 38 * 10; idx += 256) {
    int r = idx / 10, j = idx % 10;
    int gr = r0 + r, gc = c0m4 + 4 * j;
    float4 v4;
    float* vp = (float*)&v4;
    if ((u32)gr < (u32)HW && gc >= 0 && gc + 3 < HW) {
      float4 Rv = *(const float4*)&R[(size_t)gr * HW + gc];
      v4.x = (Rv.x > med) ? Rv.x : 0.f;
      v4.y = (Rv.y > med) ? Rv.y : 0.f;
      v4.z = (Rv.z > med) ? Rv.z : 0.f;
      v4.w = (Rv.w > med) ? Rv.w : 0.f;
    } else {
#pragma unroll
      for (int t = 0; t < 4; ++t) {
        int g2 = gc + t;
        float val = -INFINITY;
        if ((u32)gr < (u32)HW && (u32)g2 < (u32)HW) {
          float Rv = R[(size_t)gr * HW + g2];
          val = (Rv > med) ? Rv : 0.f;
        }
        vp[t] = val;
      }
    }
    *(float4*)&rt[r][4 * j] = v4;
  }
  __syncthreads();
  // horizontal 7-max: hm[r][c] = max rt[r][c+1 .. c+7]
  for (int idx = threadIdx.x; idx < 38 * TS; idx += 256) {
    int r = idx / TS, c = idx % TS;
    float m = rt[r][c + 1];
#pragma unroll
    for (int k = 2; k < 8; ++k) m = fmaxf(m, rt[r][c + k]);
    hm[r][c] = m;
  }
  __syncthreads();
  // vertical 7-max + NMS mask
  for (int idx = threadIdx.x; idx < TS * TS; idx += 256) {
    int r = idx / TS, c = idx % TS;
    float pooled = hm[r][c];
#pragma unroll
    for (int k = 1; k < 7; ++k) pooled = fmaxf(pooled, hm[r + k][c]);
    float rc = rt[r + 3][c + 4];
    out[(size_t)(r0 + 3 + r) * HW + (c0 + c)] = (rc == pooled) ? rc : 0.f;
  }
}

// ---------------------------------------------------------------------------
extern "C" void kernel_launch(void* const* d_in, const int* in_sizes, int n_in,
                              void* d_out, int out_size, void* d_ws,
                              size_t ws_size, hipStream_t stream) {
  (void)in_sizes;
  (void)n_in;
  (void)out_size;
  const float* x = (const float*)d_in[0];
  const float* gw = (const float*)d_in[2];  // d_in[1] (sobel weights) baked in
  float* out = (float*)d_out;

  const size_t RB = (size_t)NPIX * sizeof(float);
  // h1: 16x1024, h2: 4x4096, h3: 4x1024, sel: 8, wcnt: 64
  const size_t HN =
      H1_COPIES * 1024 + H23_COPIES * 4096 + H23_COPIES * 1024 + 8 + NSTRIPE;
  const size_t HB = HN * sizeof(u32);
  const bool planA = ws_size >= RB + HB;

  float* Rbuf;
  u32* hb;
  if (planA) {
    Rbuf = (float*)d_ws;
    hb = (u32*)((char*)d_ws + RB);
  } else {
    Rbuf = out;  // fallback: R staged in d_out; final pass recomputes per-tile
    hb = (u32*)d_ws;
  }
  u32* h1 = hb;
  u32* h2 = h1 + H1_COPIES * 1024;
  u32* h3 = h2 + H23_COPIES * 4096;
  u32* sel = h3 + H23_COPIES * 1024;
  u32* wcnt = sel + 8;

  // compaction buffer from spare workspace (fallback-safe if too small)
  u32 segcap = 0;
  u32* cbuf = nullptr;
  const size_t used = (planA ? RB : 0) + HB;
  if (planA && ws_size > used + 4096) {
    size_t spare = (ws_size - used) / sizeof(u32);
    size_t sc = spare / NSTRIPE;
    if (sc > (size_t)(NPIX / NSTRIPE)) sc = NPIX / NSTRIPE;
    segcap = (u32)sc;
    cbuf = (u32*)((char*)d_ws + used);
  }

  dim3 grid(HW / TS, HW / TS);
  hipMemsetAsync(hb, 0, HB, stream);
  harris_main<32, false><<<grid, 256, 0, stream>>>(x, gw, nullptr, Rbuf, h1);
  scan_select<1024, H1_COPIES, 22, true, false><<<1, 256, 0, stream>>>(h1, sel);
  hist_pass2<<<1024, 256, 0, stream>>>((const float4*)Rbuf, sel, h2, wcnt, cbuf,
                                       segcap);
  scan_select<4096, H23_COPIES, 10, false, false><<<1, 256, 0, stream>>>(h2,
                                                                         sel);
  hist_pass3<<<1024, 256, 0, stream>>>((const float4*)Rbuf, sel, wcnt, cbuf,
                                       segcap, h3);
  scan_select<1024, H23_COPIES, 0, false, true><<<1, 256, 0, stream>>>(h3, sel);
  if (planA) {
    final_pool<<<grid, 256, 0, stream>>>(Rbuf, sel, out);
  } else {
    harris_main<38, true><<<grid, 256, 0, stream>>>(x, gw, sel, out, nullptr);
  }
}

// Round 11
// 309.429 us; speedup vs baseline: 1.8672x; 1.8672x over previous
//
#include <hip/hip_runtime.h>
#include <math.h>

#define HW 4096
#define NPIX (HW * HW)        // 16777216
#define N4 (NPIX / 4)         // 4194304
#define TS 32
#define MED_RANK 8388607u     // floor(0.5*(N-1)), method='lower'
#define NOBIN 0xFFFFFFFFu
#define H1_COPIES 16
#define H23_COPIES 4

typedef unsigned int u32;
typedef unsigned long long u64;

__device__ __forceinline__ u32 f2key(float f) {
  u32 u = __float_as_uint(f);
  return (u & 0x80000000u) ? ~u : (u | 0x80000000u);
}

// Wave-aggregated LDS histogram add: one atomic per same-bin run across the
// wave (R is spatially smooth -> long runs). Requires ALL 64 lanes active.
__device__ __forceinline__ void wave_hist_add(u32* lh, u32 bin) {
  int lane = threadIdx.x & 63;
  u32 prev = __shfl_up(bin, 1);
  bool head = (lane == 0) || (prev != bin);
  u64 hb = __ballot(head);
  u64 after = (lane < 63) ? (hb >> (lane + 1)) : 0ull;
  int run = after ? __ffsll((long long)after) : (64 - lane);
  if (head && bin != NOBIN) atomicAdd(&lh[bin], (u32)run);
}

// ---------------------------------------------------------------------------
// Fused Sobel -> products -> separable 9x9 Gaussian -> Harris R.
// POOL=false: RT=32, write R tile + fused 1024-bin (top-10-bit) histogram
//             (merged into one of H1_COPIES striped global copies).
// POOL=true (fallback, no ws for R): RT=38 w/ halo 3, threshold+7x7 NMS.
// ---------------------------------------------------------------------------
template <int RT, bool POOL>
__global__ __launch_bounds__(256, 4) void harris_main(
    const float* __restrict__ x, const float* __restrict__ gw,
    const u32* __restrict__ sel, float* __restrict__ Rout,
    u32* __restrict__ h1) {
  constexpr int PR = RT + 8;            // products region (Gauss halo 4)
  constexpr int XR = RT + 10;           // input region (+ Sobel halo 1)
  constexpr int CGR = (RT + 3) / 4;     // 4-wide col groups
  constexpr int VP = ((((CGR - 1) * 4 + 12) + 3) / 4) * 4 + 4;  // v stride,
  // padded to 44 (RT=32): bank starts 12r mod 32 -> uniform 8 dwords/bank
  constexpr int RTD = POOL ? RT : 1;
  constexpr int NH = POOL ? 1 : 1024;
  constexpr int XIN_F = XR * (XR + 2);
  constexpr int V_F = 3 * RT * VP;
  constexpr int UNI_F = (XIN_F > V_F) ? XIN_F : V_F;

  // xin and v have disjoint lifetimes (barrier-separated) -> union them
  __shared__ __align__(16) float uni[UNI_F];
  __shared__ float p0[PR][PR], p1[PR][PR], p2[PR][PR];
  __shared__ float g1s[12];
  __shared__ float rt[RTD][RTD + 2];
  __shared__ float hm[RTD][TS];
  __shared__ u32 lh[NH];

  float(*xin)[XR + 2] = (float(*)[XR + 2])uni;  // [XR][XR+2]
  float(*v)[VP] = (float(*)[VP])uni;            // [3*RT][VP]

  const int tid = threadIdx.x;
  const int or0 = blockIdx.y * TS - (POOL ? 3 : 0);
  const int oc0 = blockIdx.x * TS - (POOL ? 3 : 0);
  const int xr0 = or0 - 5, xc0 = oc0 - 5;
  const bool inter =
      (xr0 >= 0) && (xc0 >= 0) && (xr0 + XR <= HW) && (xc0 + XR <= HW);

  if constexpr (!POOL)
    for (int i = tid; i < NH; i += 256) lh[i] = 0u;

  // 1D normalized gaussian taps = row sums of the normalized 2D kernel
  if (tid < 9) {
    float s = 0.f;
#pragma unroll
    for (int j = 0; j < 9; ++j) s += gw[tid * 9 + j];
    g1s[tid] = s;
  }

  // stage input tile (zero-padded); interior fast path skips guards
  if (inter) {
    for (int idx = tid; idx < XR * XR; idx += 256) {
      int r = idx / XR, c = idx % XR;
      xin[r][c] = x[(size_t)(xr0 + r) * HW + (xc0 + c)];
    }
  } else {
    for (int idx = tid; idx < XR * XR; idx += 256) {
      int r = idx / XR, c = idx % XR;
      int gr = xr0 + r, gc = xc0 + c;
      float val = 0.f;
      if ((u32)gr < (u32)HW && (u32)gc < (u32)HW) val = x[(size_t)gr * HW + gc];
      xin[r][c] = val;
    }
  }
  __syncthreads();

  // Sobel + products (zero outside image)
  if constexpr (!POOL) {
    // vectorized: 4 products/task via float4 LDS ops (PR=40 divisible by 4)
    for (int task = tid; task < PR * (PR / 4); task += 256) {
      int r = task / (PR / 4);
      int c4 = (task % (PR / 4)) * 4;
      __align__(16) float a[3][8];
#pragma unroll
      for (int rr = 0; rr < 3; ++rr) {
        *(float4*)&a[rr][0] = *(const float4*)&xin[r + rr][c4];
        *(float4*)&a[rr][4] = *(const float4*)&xin[r + rr][c4 + 4];
      }
      float4 P0, P1, P2;
      float* p0v = (float*)&P0;
      float* p1v = (float*)&P1;
      float* p2v = (float*)&P2;
      if (inter) {
#pragma unroll
        for (int o = 0; o < 4; ++o) {
          float Ix = (a[0][o + 2] - a[0][o]) + 2.f * (a[1][o + 2] - a[1][o]) +
                     (a[2][o + 2] - a[2][o]);
          float Iy = (a[2][o] - a[0][o]) + 2.f * (a[2][o + 1] - a[0][o + 1]) +
                     (a[2][o + 2] - a[0][o + 2]);
          p0v[o] = Ix * Ix;
          p1v[o] = Iy * Iy;
          p2v[o] = Ix * Iy;
        }
      } else {
        int gr = or0 - 4 + r;
        int gc0 = oc0 - 4 + c4;
#pragma unroll
        for (int o = 0; o < 4; ++o) {
          float Ix = (a[0][o + 2] - a[0][o]) + 2.f * (a[1][o + 2] - a[1][o]) +
                     (a[2][o + 2] - a[2][o]);
          float Iy = (a[2][o] - a[0][o]) + 2.f * (a[2][o + 1] - a[0][o + 1]) +
                     (a[2][o + 2] - a[0][o + 2]);
          bool in = ((u32)gr < (u32)HW) && ((u32)(gc0 + o) < (u32)HW);
          p0v[o] = in ? Ix * Ix : 0.f;
          p1v[o] = in ? Iy * Iy : 0.f;
          p2v[o] = in ? Ix * Iy : 0.f;
        }
      }
      *(float4*)&p0[r][c4] = P0;
      *(float4*)&p1[r][c4] = P1;
      *(float4*)&p2[r][c4] = P2;
    }
  } else {
    for (int idx = tid; idx < PR * PR; idx += 256) {
      int r = idx / PR, c = idx % PR;
      int gr = or0 - 4 + r, gc = oc0 - 4 + c;
      float P0 = 0.f, P1 = 0.f, P2 = 0.f;
      if ((u32)gr < (u32)HW && (u32)gc < (u32)HW) {
        float a00 = xin[r][c], a01 = xin[r][c + 1], a02 = xin[r][c + 2];
        float a10 = xin[r + 1][c], a12 = xin[r + 1][c + 2];
        float a20 = xin[r + 2][c], a21 = xin[r + 2][c + 1],
              a22 = xin[r + 2][c + 2];
        float Ix = (a02 - a00) + 2.f * (a12 - a10) + (a22 - a20);
        float Iy = (a20 - a00) + 2.f * (a21 - a01) + (a22 - a02);
        P0 = Ix * Ix;
        P1 = Iy * Iy;
        P2 = Ix * Iy;
      }
      p0[r][c] = P0;
      p1[r][c] = P1;
      p2[r][c] = P2;
    }
  }
  __syncthreads();  // also: last read of xin before v overwrites uni

  float g[9];
#pragma unroll
  for (int k = 0; k < 9; ++k) g[k] = g1s[k];

  // vertical 9-tap (writes v, overwriting xin region)
  if constexpr (!POOL) {
    // float4 across columns: 240 single-iteration tasks =
    // 3 ch x 8 row-groups(4) x 10 col-quads; 12 quad reads -> 4 quad writes
    if (tid < 240) {
      int ch = tid / 80;
      int rem = tid - ch * 80;
      int rg = (rem / 10) * 4;
      int c4 = (rem % 10) * 4;
      const float(*pp)[PR] = (ch == 0) ? p0 : (ch == 1) ? p1 : p2;
      float4 col[12];
#pragma unroll
      for (int k = 0; k < 12; ++k) col[k] = *(const float4*)&pp[rg + k][c4];
#pragma unroll
      for (int o = 0; o < 4; ++o) {
        float4 s = {0.f, 0.f, 0.f, 0.f};
#pragma unroll
        for (int k = 0; k < 9; ++k) {
          float4 cv = col[o + k];
          s.x = fmaf(g[k], cv.x, s.x);
          s.y = fmaf(g[k], cv.y, s.y);
          s.z = fmaf(g[k], cv.z, s.z);
          s.w = fmaf(g[k], cv.w, s.w);
        }
        *(float4*)&v[ch * RT + rg + o][c4] = s;
      }
    }
  } else {
    for (int task = tid; task < 3 * CGR * PR; task += 256) {
      int ch = task / (CGR * PR);
      int rem = task % (CGR * PR);
      int rg = (rem / PR) * 4;
      int c = rem % PR;
      const float(*pp)[PR] = (ch == 0) ? p0 : (ch == 1) ? p1 : p2;
      float col[12];
#pragma unroll
      for (int k = 0; k < 12; ++k) col[k] = (rg + k < PR) ? pp[rg + k][c] : 0.f;
#pragma unroll
      for (int o = 0; o < 4; ++o) {
        int rv = rg + o;
        if (rv < RT) {
          float s = 0.f;
#pragma unroll
          for (int k = 0; k < 9; ++k) s = fmaf(g[k], col[o + k], s);
          v[ch * RT + rv][c] = s;
        }
      }
    }
  }
  __syncthreads();

  float med = 0.f;
  if (POOL) med = __uint_as_float(sel[2]);

  // horizontal 9-tap + Harris R (4 cols/task, float4 LDS reads)
  for (int task = tid; task < RT * CGR; task += 256) {
    int r = task / CGR;
    int c0i = (task % CGR) * 4;
    float s3[3][4];
#pragma unroll
    for (int ch = 0; ch < 3; ++ch) {
      const float4* vp = (const float4*)&v[ch * RT + r][c0i];
      float4 w0 = vp[0], w1 = vp[1], w2 = vp[2];
      float row[12] = {w0.x, w0.y, w0.z, w0.w, w1.x, w1.y,
                       w1.z, w1.w, w2.x, w2.y, w2.z, w2.w};
#pragma unroll
      for (int o = 0; o < 4; ++o) {
        float s = 0.f;
#pragma unroll
        for (int k = 0; k < 9; ++k) s = fmaf(g[k], row[o + k], s);
        s3[ch][o] = s;
      }
    }
    if constexpr (!POOL) {
      float4 rv4;
      float* rp = (float*)&rv4;
#pragma unroll
      for (int o = 0; o < 4; ++o) {
        float Sxx = s3[0][o], Syy = s3[1][o], Sxy = s3[2][o];
        float tr = Sxx + Syy;
        rp[o] = Sxx * Syy - Sxy * Sxy - 0.05f * tr * tr;
      }
      *(float4*)&Rout[(size_t)(or0 + r) * HW + (oc0 + c0i)] = rv4;
      // fused pass-1 histogram (exactly 1 loop iteration: all lanes active)
#pragma unroll
      for (int o = 0; o < 4; ++o) wave_hist_add(lh, f2key(rp[o]) >> 22);
    } else {
#pragma unroll
      for (int o = 0; o < 4; ++o) {
        int c = c0i + o;
        if (c < RT) {
          float Sxx = s3[0][o], Syy = s3[1][o], Sxy = s3[2][o];
          float tr = Sxx + Syy;
          float Rv = Sxx * Syy - Sxy * Sxy - 0.05f * tr * tr;
          int gr = or0 + r, gc = oc0 + c;
          float val = -INFINITY;
          if ((u32)gr < (u32)HW && (u32)gc < (u32)HW)
            val = (Rv > med) ? Rv : 0.f;
          rt[r][c] = val;
        }
      }
    }
  }

  if constexpr (!POOL) {
    __syncthreads();
    // striped global merge: consecutive blocks hit different copies
    const u32 cp = (u32)(blockIdx.y * gridDim.x + blockIdx.x) & (H1_COPIES - 1);
    u32* dst = h1 + cp * NH;
    for (int i = tid; i < NH; i += 256) {
      u32 c = lh[i];
      if (c) atomicAdd(&dst[i], c);
    }
  }

  if constexpr (POOL) {
    __syncthreads();
    for (int idx = tid; idx < RT * TS; idx += 256) {
      int r = idx / TS, c = idx % TS;
      float m = rt[r][c];
#pragma unroll
      for (int k = 1; k < 7; ++k) m = fmaxf(m, rt[r][c + k]);
      hm[r][c] = m;
    }
    __syncthreads();
    for (int idx = tid; idx < TS * TS; idx += 256) {
      int r = idx / TS, c = idx % TS;
      float pooled = hm[r][c];
#pragma unroll
      for (int k = 1; k < 7; ++k) pooled = fmaxf(pooled, hm[r + k][c]);
      float rc = rt[r + 3][c + 3];
      Rout[(size_t)(or0 + 3 + r) * HW + (oc0 + 3 + c)] =
          (rc == pooled) ? rc : 0.f;
    }
  }
}

// ---------------------------------------------------------------------------
// Pass 2: 12-bit histogram of keys matching the 10-bit prefix (full re-read,
// no compaction). Wave-uniform any-match skip avoids per-element cross-lane
// aggregation overhead where no lane matches (the common case).
// ---------------------------------------------------------------------------
__global__ __launch_bounds__(256) void hist_pass2(
    const float4* __restrict__ R4, const u32* __restrict__ sel,
    u32* __restrict__ hist) {
  __shared__ u32 lh[4096];
  for (int i = threadIdx.x; i < 4096; i += 256) lh[i] = 0u;
  const u32 p10 = sel[1] >> 22;
  __syncthreads();
  const u32 stride = gridDim.x * 256;
  for (u32 i = blockIdx.x * 256 + threadIdx.x; i < N4; i += stride) {
    float4 f = R4[i];
    const float* fp = (const float*)&f;
    u32 k[4];
    bool mt[4];
#pragma unroll
    for (int j = 0; j < 4; ++j) {
      k[j] = f2key(fp[j]);
      mt[j] = (k[j] >> 22) == p10;
    }
    // wave-uniform skip: only do the aggregated adds if any lane matched
    if (__ballot(mt[0] || mt[1] || mt[2] || mt[3])) {
#pragma unroll
      for (int j = 0; j < 4; ++j)
        wave_hist_add(lh, mt[j] ? ((k[j] >> 10) & 0xFFFu) : NOBIN);
    }
  }
  __syncthreads();
  u32* dst = hist + (blockIdx.x & (H23_COPIES - 1)) * 4096;
  for (int i = threadIdx.x; i < 4096; i += 256) {
    u32 c = lh[i];
    if (c) atomicAdd(&dst[i], c);
  }
}

// ---------------------------------------------------------------------------
// Pass 3: 10-bit histogram of keys matching the 22-bit prefix (full re-read).
// ---------------------------------------------------------------------------
__global__ __launch_bounds__(256) void hist_pass3(
    const float4* __restrict__ R4, const u32* __restrict__ sel,
    u32* __restrict__ hist) {
  __shared__ u32 lh[1024];
  for (int i = threadIdx.x; i < 1024; i += 256) lh[i] = 0u;
  const u32 p22 = sel[1] >> 10;
  __syncthreads();
  const u32 stride = gridDim.x * 256;
  for (u32 i = blockIdx.x * 256 + threadIdx.x; i < N4; i += stride) {
    float4 f = R4[i];
    const float* fp = (const float*)&f;
#pragma unroll
    for (int j = 0; j < 4; ++j) {
      u32 k = f2key(fp[j]);
      if ((k >> 10) == p22) atomicAdd(&lh[k & 0x3FFu], 1u);
    }
  }
  __syncthreads();
  u32* dst = hist + (blockIdx.x & (H23_COPIES - 1)) * 1024;
  for (int i = threadIdx.x; i < 1024; i += 256) {
    u32 c = lh[i];
    if (c) atomicAdd(&dst[i], c);
  }
}

// ---------------------------------------------------------------------------
// Serial rank-select within a striped histogram (sums NCOPY copies);
// updates (remaining rank, prefix); LAST also emits the median float bits.
// ---------------------------------------------------------------------------
template <int NBINS, int NCOPY, int SHIFT, bool FIRST, bool LAST>
__global__ __launch_bounds__(256) void scan_select(const u32* __restrict__ hist,
                                                   u32* __restrict__ sel) {
  __shared__ u32 part[256];
  constexpr int C = NBINS / 256;
  int tid = threadIdx.x;
  u32 s = 0;
  for (int i = 0; i < C; ++i) {
    u32 b = 0;
#pragma unroll
    for (int cp = 0; cp < NCOPY; ++cp) b += hist[cp * NBINS + tid * C + i];
    s += b;
  }
  part[tid] = s;
  __syncthreads();
  if (tid == 0) {
    u32 r = FIRST ? MED_RANK : sel[0];
    u32 cum = 0;
    int seg = 0;
    for (; seg < 255; ++seg) {
      u32 ps = part[seg];
      if (cum + ps > r) break;
      cum += ps;
    }
    int b = seg * C;
    for (int i = 0; i < C; ++i) {
      u32 h = 0;
#pragma unroll
      for (int cp = 0; cp < NCOPY; ++cp) h += hist[cp * NBINS + b];
      if (cum + h > r) break;
      cum += h;
      ++b;
    }
    sel[0] = r - cum;
    u32 pfx = (FIRST ? 0u : sel[1]) | ((u32)b << SHIFT);
    sel[1] = pfx;
    if (LAST)
      sel[2] = (pfx & 0x80000000u) ? (pfx ^ 0x80000000u) : ~pfx;
  }
}

// ---------------------------------------------------------------------------
// Threshold + 7x7 max-pool NMS from materialized R (plan A).
// float4 staging: rows r0..r0+37, cols c0-4..c0+35 (40 cols, 4-aligned).
// Needed window cols are local 1..38; cols 0,39 are alignment padding.
// ---------------------------------------------------------------------------
__global__ __launch_bounds__(256) void final_pool(const float* __restrict__ R,
                                                  const u32* __restrict__ sel,
                                                  float* __restrict__ out) {
  __shared__ __align__(16) float rt[38][44];
  __shared__ float hm[38][32];
  const float med = __uint_as_float(sel[2]);
  const int r0 = blockIdx.y * TS - 3;
  const int c0 = blockIdx.x * TS;
  const int c0m4 = c0 - 4;
  // stage + threshold (float4)
  for (int idx = threadIdx.x; idx < 38 * 10; idx += 256) {
    int r = idx / 10, j = idx % 10;
    int gr = r0 + r, gc = c0m4 + 4 * j;
    float4 v4;
    float* vp = (float*)&v4;
    if ((u32)gr < (u32)HW && gc >= 0 && gc + 3 < HW) {
      float4 Rv = *(const float4*)&R[(size_t)gr * HW + gc];
      v4.x = (Rv.x > med) ? Rv.x : 0.f;
      v4.y = (Rv.y > med) ? Rv.y : 0.f;
      v4.z = (Rv.z > med) ? Rv.z : 0.f;
      v4.w = (Rv.w > med) ? Rv.w : 0.f;
    } else {
#pragma unroll
      for (int t = 0; t < 4; ++t) {
        int g2 = gc + t;
        float val = -INFINITY;
        if ((u32)gr < (u32)HW && (u32)g2 < (u32)HW) {
          float Rv = R[(size_t)gr * HW + g2];
          val = (Rv > med) ? Rv : 0.f;
        }
        vp[t] = val;
      }
    }
    *(float4*)&rt[r][4 * j] = v4;
  }
  __syncthreads();
  // horizontal 7-max: hm[r][c] = max rt[r][c+1 .. c+7]
  for (int idx = threadIdx.x; idx < 38 * TS; idx += 256) {
    int r = idx / TS, c = idx % TS;
    float m = rt[r][c + 1];
#pragma unroll
    for (int k = 2; k < 8; ++k) m = fmaxf(m, rt[r][c + k]);
    hm[r][c] = m;
  }
  __syncthreads();
  // vertical 7-max + NMS mask
  for (int idx = threadIdx.x; idx < TS * TS; idx += 256) {
    int r = idx / TS, c = idx % TS;
    float pooled = hm[r][c];
#pragma unroll
    for (int k = 1; k < 7; ++k) pooled = fmaxf(pooled, hm[r + k][c]);
    float rc = rt[r + 3][c + 4];
    out[(size_t)(r0 + 3 + r) * HW + (c0 + c)] = (rc == pooled) ? rc : 0.f;
  }
}

// ---------------------------------------------------------------------------
extern "C" void kernel_launch(void* const* d_in, const int* in_sizes, int n_in,
                              void* d_out, int out_size, void* d_ws,
                              size_t ws_size, hipStream_t stream) {
  (void)in_sizes;
  (void)n_in;
  (void)out_size;
  const float* x = (const float*)d_in[0];
  const float* gw = (const float*)d_in[2];  // d_in[1] (sobel weights) baked in
  float* out = (float*)d_out;

  const size_t RB = (size_t)NPIX * sizeof(float);
  // h1: 16x1024, h2: 4x4096, h3: 4x1024, sel: 8
  const size_t HN = H1_COPIES * 1024 + H23_COPIES * 4096 + H23_COPIES * 1024 + 8;
  const size_t HB = HN * sizeof(u32);  // ~147 KB
  const bool planA = ws_size >= RB + HB;

  float* Rbuf;
  u32* hb;
  if (planA) {
    Rbuf = (float*)d_ws;
    hb = (u32*)((char*)d_ws + RB);
  } else {
    Rbuf = out;  // fallback: R staged in d_out; final pass recomputes per-tile
    hb = (u32*)d_ws;
  }
  u32* h1 = hb;
  u32* h2 = h1 + H1_COPIES * 1024;
  u32* h3 = h2 + H23_COPIES * 4096;
  u32* sel = h3 + H23_COPIES * 1024;

  dim3 grid(HW / TS, HW / TS);
  hipMemsetAsync(hb, 0, HB, stream);
  harris_main<32, false><<<grid, 256, 0, stream>>>(x, gw, nullptr, Rbuf, h1);
  scan_select<1024, H1_COPIES, 22, true, false><<<1, 256, 0, stream>>>(h1, sel);
  hist_pass2<<<1024, 256, 0, stream>>>((const float4*)Rbuf, sel, h2);
  scan_select<4096, H23_COPIES, 10, false, false><<<1, 256, 0, stream>>>(h2,
                                                                         sel);
  hist_pass3<<<1024, 256, 0, stream>>>((const float4*)Rbuf, sel, h3);
  scan_select<1024, H23_COPIES, 0, false, true><<<1, 256, 0, stream>>>(h3, sel);
  if (planA) {
    final_pool<<<grid, 256, 0, stream>>>(Rbuf, sel, out);
  } else {
    harris_main<38, true><<<grid, 256, 0, stream>>>(x, gw, sel, out, nullptr);
  }
}

// Round 12
// 307.967 us; speedup vs baseline: 1.8760x; 1.0047x over previous
//
#include <hip/hip_runtime.h>
#include <math.h>

#define HW 4096
#define NPIX (HW * HW)        // 16777216
#define N4 (NPIX / 4)         // 4194304
#define TS 32
#define MED_RANK 8388607u     // floor(0.5*(N-1)), method='lower'
#define NOBIN 0xFFFFFFFFu
#define H1_COPIES 16
#define H23_COPIES 4

typedef unsigned int u32;
typedef unsigned long long u64;

__device__ __forceinline__ u32 f2key(float f) {
  u32 u = __float_as_uint(f);
  return (u & 0x80000000u) ? ~u : (u | 0x80000000u);
}

// Wave-aggregated LDS histogram add: one atomic per same-bin run across the
// wave (R is spatially smooth -> long runs). Requires ALL 64 lanes active.
__device__ __forceinline__ void wave_hist_add(u32* lh, u32 bin) {
  int lane = threadIdx.x & 63;
  u32 prev = __shfl_up(bin, 1);
  bool head = (lane == 0) || (prev != bin);
  u64 hb = __ballot(head);
  u64 after = (lane < 63) ? (hb >> (lane + 1)) : 0ull;
  int run = after ? __ffsll((long long)after) : (64 - lane);
  if (head && bin != NOBIN) atomicAdd(&lh[bin], (u32)run);
}

// ---------------------------------------------------------------------------
// Fused Sobel -> products -> separable 9x9 Gaussian -> Harris R.
// POOL=false: RT=32, write R tile + fused 1024-bin (top-10-bit) histogram
//             (merged into one of H1_COPIES striped global copies).
// POOL=true (fallback, no ws for R): RT=38 w/ halo 3, threshold+7x7 NMS.
// Bank layout: p stride 44 (rows 4 apart -> +16 banks, spreads float4
// vertical reads); v stride 40 (8-lane x 3-quad horizontal reads uniform).
// ---------------------------------------------------------------------------
template <int RT, bool POOL>
__global__ __launch_bounds__(256, 4) void harris_main(
    const float* __restrict__ x, const float* __restrict__ gw,
    const u32* __restrict__ sel, float* __restrict__ Rout,
    u32* __restrict__ h1) {
  constexpr int PR = RT + 8;            // products region (Gauss halo 4)
  constexpr int PRP = 44;               // p row stride (banks: 12r mod 32)
  constexpr int XR = RT + 10;           // input region (+ Sobel halo 1)
  constexpr int CGR = (RT + 3) / 4;     // 4-wide col groups
  constexpr int VP = POOL ? ((((CGR - 1) * 4 + 12) + 3) / 4) * 4 + 4 : 40;
  constexpr int RTD = POOL ? RT : 1;
  constexpr int NH = POOL ? 1 : 1024;
  constexpr int XIN_F = XR * (XR + 2);
  constexpr int V_F = 3 * RT * VP;
  constexpr int UNI_F = (XIN_F > V_F) ? XIN_F : V_F;

  // xin and v have disjoint lifetimes (barrier-separated) -> union them
  __shared__ __align__(16) float uni[UNI_F];
  __shared__ float p0[PR][PRP], p1[PR][PRP], p2[PR][PRP];
  __shared__ float g1s[9];
  __shared__ float rt[RTD][RTD + 2];
  __shared__ float hm[RTD][POOL ? TS : 1];
  __shared__ u32 lh[NH];

  float(*xin)[XR + 2] = (float(*)[XR + 2])uni;  // [XR][XR+2]
  float(*v)[VP] = (float(*)[VP])uni;            // [3*RT][VP]

  const int tid = threadIdx.x;
  const int or0 = blockIdx.y * TS - (POOL ? 3 : 0);
  const int oc0 = blockIdx.x * TS - (POOL ? 3 : 0);
  const int xr0 = or0 - 5, xc0 = oc0 - 5;
  const bool inter =
      (xr0 >= 0) && (xc0 >= 0) && (xr0 + XR <= HW) && (xc0 + XR <= HW);

  if constexpr (!POOL)
    for (int i = tid; i < NH; i += 256) lh[i] = 0u;

  // 1D normalized gaussian taps = row sums of the normalized 2D kernel
  if (tid < 9) {
    float s = 0.f;
#pragma unroll
    for (int j = 0; j < 9; ++j) s += gw[tid * 9 + j];
    g1s[tid] = s;
  }

  // stage input tile (zero-padded); interior fast path skips guards
  if (inter) {
    for (int idx = tid; idx < XR * XR; idx += 256) {
      int r = idx / XR, c = idx % XR;
      xin[r][c] = x[(size_t)(xr0 + r) * HW + (xc0 + c)];
    }
  } else {
    for (int idx = tid; idx < XR * XR; idx += 256) {
      int r = idx / XR, c = idx % XR;
      int gr = xr0 + r, gc = xc0 + c;
      float val = 0.f;
      if ((u32)gr < (u32)HW && (u32)gc < (u32)HW) val = x[(size_t)gr * HW + gc];
      xin[r][c] = val;
    }
  }
  __syncthreads();

  // Sobel + products (zero outside image)
  if constexpr (!POOL) {
    // vectorized: 4 products/task via float4 LDS ops (PR=40 divisible by 4)
    for (int task = tid; task < PR * (PR / 4); task += 256) {
      int r = task / (PR / 4);
      int c4 = (task % (PR / 4)) * 4;
      __align__(16) float a[3][8];
#pragma unroll
      for (int rr = 0; rr < 3; ++rr) {
        *(float4*)&a[rr][0] = *(const float4*)&xin[r + rr][c4];
        *(float4*)&a[rr][4] = *(const float4*)&xin[r + rr][c4 + 4];
      }
      float4 P0, P1, P2;
      float* p0v = (float*)&P0;
      float* p1v = (float*)&P1;
      float* p2v = (float*)&P2;
      if (inter) {
#pragma unroll
        for (int o = 0; o < 4; ++o) {
          float Ix = (a[0][o + 2] - a[0][o]) + 2.f * (a[1][o + 2] - a[1][o]) +
                     (a[2][o + 2] - a[2][o]);
          float Iy = (a[2][o] - a[0][o]) + 2.f * (a[2][o + 1] - a[0][o + 1]) +
                     (a[2][o + 2] - a[0][o + 2]);
          p0v[o] = Ix * Ix;
          p1v[o] = Iy * Iy;
          p2v[o] = Ix * Iy;
        }
      } else {
        int gr = or0 - 4 + r;
        int gc0 = oc0 - 4 + c4;
#pragma unroll
        for (int o = 0; o < 4; ++o) {
          float Ix = (a[0][o + 2] - a[0][o]) + 2.f * (a[1][o + 2] - a[1][o]) +
                     (a[2][o + 2] - a[2][o]);
          float Iy = (a[2][o] - a[0][o]) + 2.f * (a[2][o + 1] - a[0][o + 1]) +
                     (a[2][o + 2] - a[0][o + 2]);
          bool in = ((u32)gr < (u32)HW) && ((u32)(gc0 + o) < (u32)HW);
          p0v[o] = in ? Ix * Ix : 0.f;
          p1v[o] = in ? Iy * Iy : 0.f;
          p2v[o] = in ? Ix * Iy : 0.f;
        }
      }
      *(float4*)&p0[r][c4] = P0;
      *(float4*)&p1[r][c4] = P1;
      *(float4*)&p2[r][c4] = P2;
    }
  } else {
    for (int idx = tid; idx < PR * PR; idx += 256) {
      int r = idx / PR, c = idx % PR;
      int gr = or0 - 4 + r, gc = oc0 - 4 + c;
      float P0 = 0.f, P1 = 0.f, P2 = 0.f;
      if ((u32)gr < (u32)HW && (u32)gc < (u32)HW) {
        float a00 = xin[r][c], a01 = xin[r][c + 1], a02 = xin[r][c + 2];
        float a10 = xin[r + 1][c], a12 = xin[r + 1][c + 2];
        float a20 = xin[r + 2][c], a21 = xin[r + 2][c + 1],
              a22 = xin[r + 2][c + 2];
        float Ix = (a02 - a00) + 2.f * (a12 - a10) + (a22 - a20);
        float Iy = (a20 - a00) + 2.f * (a21 - a01) + (a22 - a02);
        P0 = Ix * Ix;
        P1 = Iy * Iy;
        P2 = Ix * Iy;
      }
      p0[r][c] = P0;
      p1[r][c] = P1;
      p2[r][c] = P2;
    }
  }
  __syncthreads();  // also: last read of xin before v overwrites uni

  float g[9];
#pragma unroll
  for (int k = 0; k < 9; ++k) g[k] = g1s[k];

  // vertical 9-tap (writes v, overwriting xin region)
  if constexpr (!POOL) {
    // float4 across columns: 240 single-iteration tasks =
    // 3 ch x 8 row-groups(4) x 10 col-quads; 12 quad reads -> 4 quad writes
    if (tid < 240) {
      int ch = tid / 80;
      int rem = tid - ch * 80;
      int rg = (rem / 10) * 4;
      int c4 = (rem % 10) * 4;
      const float(*pp)[PRP] = (ch == 0) ? p0 : (ch == 1) ? p1 : p2;
      float4 col[12];
#pragma unroll
      for (int k = 0; k < 12; ++k) col[k] = *(const float4*)&pp[rg + k][c4];
#pragma unroll
      for (int o = 0; o < 4; ++o) {
        float4 s = {0.f, 0.f, 0.f, 0.f};
#pragma unroll
        for (int k = 0; k < 9; ++k) {
          float4 cv = col[o + k];
          s.x = fmaf(g[k], cv.x, s.x);
          s.y = fmaf(g[k], cv.y, s.y);
          s.z = fmaf(g[k], cv.z, s.z);
          s.w = fmaf(g[k], cv.w, s.w);
        }
        *(float4*)&v[ch * RT + rg + o][c4] = s;
      }
    }
  } else {
    for (int task = tid; task < 3 * CGR * PR; task += 256) {
      int ch = task / (CGR * PR);
      int rem = task % (CGR * PR);
      int rg = (rem / PR) * 4;
      int c = rem % PR;
      const float(*pp)[PRP] = (ch == 0) ? p0 : (ch == 1) ? p1 : p2;
      float col[12];
#pragma unroll
      for (int k = 0; k < 12; ++k) col[k] = (rg + k < PR) ? pp[rg + k][c] : 0.f;
#pragma unroll
      for (int o = 0; o < 4; ++o) {
        int rv = rg + o;
        if (rv < RT) {
          float s = 0.f;
#pragma unroll
          for (int k = 0; k < 9; ++k) s = fmaf(g[k], col[o + k], s);
          v[ch * RT + rv][c] = s;
        }
      }
    }
  }
  __syncthreads();

  float med = 0.f;
  if (POOL) med = __uint_as_float(sel[2]);

  // horizontal 9-tap + Harris R (4 cols/task, float4 LDS reads)
  for (int task = tid; task < RT * CGR; task += 256) {
    int r = task / CGR;
    int c0i = (task % CGR) * 4;
    float s3[3][4];
#pragma unroll
    for (int ch = 0; ch < 3; ++ch) {
      const float4* vp = (const float4*)&v[ch * RT + r][c0i];
      float4 w0 = vp[0], w1 = vp[1], w2 = vp[2];
      float row[12] = {w0.x, w0.y, w0.z, w0.w, w1.x, w1.y,
                       w1.z, w1.w, w2.x, w2.y, w2.z, w2.w};
#pragma unroll
      for (int o = 0; o < 4; ++o) {
        float s = 0.f;
#pragma unroll
        for (int k = 0; k < 9; ++k) s = fmaf(g[k], row[o + k], s);
        s3[ch][o] = s;
      }
    }
    if constexpr (!POOL) {
      float4 rv4;
      float* rp = (float*)&rv4;
#pragma unroll
      for (int o = 0; o < 4; ++o) {
        float Sxx = s3[0][o], Syy = s3[1][o], Sxy = s3[2][o];
        float tr = Sxx + Syy;
        rp[o] = Sxx * Syy - Sxy * Sxy - 0.05f * tr * tr;
      }
      *(float4*)&Rout[(size_t)(or0 + r) * HW + (oc0 + c0i)] = rv4;
      // fused pass-1 histogram (exactly 1 loop iteration: all lanes active)
#pragma unroll
      for (int o = 0; o < 4; ++o) wave_hist_add(lh, f2key(rp[o]) >> 22);
    } else {
#pragma unroll
      for (int o = 0; o < 4; ++o) {
        int c = c0i + o;
        if (c < RT) {
          float Sxx = s3[0][o], Syy = s3[1][o], Sxy = s3[2][o];
          float tr = Sxx + Syy;
          float Rv = Sxx * Syy - Sxy * Sxy - 0.05f * tr * tr;
          int gr = or0 + r, gc = oc0 + c;
          float val = -INFINITY;
          if ((u32)gr < (u32)HW && (u32)gc < (u32)HW)
            val = (Rv > med) ? Rv : 0.f;
          rt[r][c] = val;
        }
      }
    }
  }

  if constexpr (!POOL) {
    __syncthreads();
    // striped global merge: consecutive blocks hit different copies
    const u32 cp = (u32)(blockIdx.y * gridDim.x + blockIdx.x) & (H1_COPIES - 1);
    u32* dst = h1 + cp * NH;
    for (int i = tid; i < NH; i += 256) {
      u32 c = lh[i];
      if (c) atomicAdd(&dst[i], c);
    }
  }

  if constexpr (POOL) {
    __syncthreads();
    for (int idx = tid; idx < RT * TS; idx += 256) {
      int r = idx / TS, c = idx % TS;
      float m = rt[r][c];
#pragma unroll
      for (int k = 1; k < 7; ++k) m = fmaxf(m, rt[r][c + k]);
      hm[r][c] = m;
    }
    __syncthreads();
    for (int idx = tid; idx < TS * TS; idx += 256) {
      int r = idx / TS, c = idx % TS;
      float pooled = hm[r][c];
#pragma unroll
      for (int k = 1; k < 7; ++k) pooled = fmaxf(pooled, hm[r + k][c]);
      float rc = rt[r + 3][c + 3];
      Rout[(size_t)(or0 + 3 + r) * HW + (oc0 + 3 + c)] =
          (rc == pooled) ? rc : 0.f;
    }
  }
}

// ---------------------------------------------------------------------------
// Pass 2: 12-bit histogram of keys matching the 10-bit prefix (full re-read,
// no compaction). Wave-uniform any-match skip avoids per-element cross-lane
// aggregation overhead where no lane matches (the common case).
// ---------------------------------------------------------------------------
__global__ __launch_bounds__(256) void hist_pass2(
    const float4* __restrict__ R4, const u32* __restrict__ sel,
    u32* __restrict__ hist) {
  __shared__ u32 lh[4096];
  for (int i = threadIdx.x; i < 4096; i += 256) lh[i] = 0u;
  const u32 p10 = sel[1] >> 22;
  __syncthreads();
  const u32 stride = gridDim.x * 256;
  for (u32 i = blockIdx.x * 256 + threadIdx.x; i < N4; i += stride) {
    float4 f = R4[i];
    const float* fp = (const float*)&f;
    u32 k[4];
    bool mt[4];
#pragma unroll
    for (int j = 0; j < 4; ++j) {
      k[j] = f2key(fp[j]);
      mt[j] = (k[j] >> 22) == p10;
    }
    // wave-uniform skip: only do the aggregated adds if any lane matched
    if (__ballot(mt[0] || mt[1] || mt[2] || mt[3])) {
#pragma unroll
      for (int j = 0; j < 4; ++j)
        wave_hist_add(lh, mt[j] ? ((k[j] >> 10) & 0xFFFu) : NOBIN);
    }
  }
  __syncthreads();
  u32* dst = hist + (blockIdx.x & (H23_COPIES - 1)) * 4096;
  for (int i = threadIdx.x; i < 4096; i += 256) {
    u32 c = lh[i];
    if (c) atomicAdd(&dst[i], c);
  }
}

// ---------------------------------------------------------------------------
// Pass 3: 10-bit histogram of keys matching the 22-bit prefix (full re-read).
// Ballot-skip: matching keys are very rare at 22-bit specificity.
// ---------------------------------------------------------------------------
__global__ __launch_bounds__(256) void hist_pass3(
    const float4* __restrict__ R4, const u32* __restrict__ sel,
    u32* __restrict__ hist) {
  __shared__ u32 lh[1024];
  for (int i = threadIdx.x; i < 1024; i += 256) lh[i] = 0u;
  const u32 p22 = sel[1] >> 10;
  __syncthreads();
  const u32 stride = gridDim.x * 256;
  for (u32 i = blockIdx.x * 256 + threadIdx.x; i < N4; i += stride) {
    float4 f = R4[i];
    const float* fp = (const float*)&f;
    u32 k[4];
    bool mt[4];
#pragma unroll
    for (int j = 0; j < 4; ++j) {
      k[j] = f2key(fp[j]);
      mt[j] = (k[j] >> 10) == p22;
    }
    if (__ballot(mt[0] || mt[1] || mt[2] || mt[3])) {
#pragma unroll
      for (int j = 0; j < 4; ++j)
        if (mt[j]) atomicAdd(&lh[k[j] & 0x3FFu], 1u);
    }
  }
  __syncthreads();
  u32* dst = hist + (blockIdx.x & (H23_COPIES - 1)) * 1024;
  for (int i = threadIdx.x; i < 1024; i += 256) {
    u32 c = lh[i];
    if (c) atomicAdd(&dst[i], c);
  }
}

// ---------------------------------------------------------------------------
// Serial rank-select within a striped histogram (sums NCOPY copies);
// updates (remaining rank, prefix); LAST also emits the median float bits.
// ---------------------------------------------------------------------------
template <int NBINS, int NCOPY, int SHIFT, bool FIRST, bool LAST>
__global__ __launch_bounds__(256) void scan_select(const u32* __restrict__ hist,
                                                   u32* __restrict__ sel) {
  __shared__ u32 part[256];
  constexpr int C = NBINS / 256;
  int tid = threadIdx.x;
  u32 s = 0;
  for (int i = 0; i < C; ++i) {
    u32 b = 0;
#pragma unroll
    for (int cp = 0; cp < NCOPY; ++cp) b += hist[cp * NBINS + tid * C + i];
    s += b;
  }
  part[tid] = s;
  __syncthreads();
  if (tid == 0) {
    u32 r = FIRST ? MED_RANK : sel[0];
    u32 cum = 0;
    int seg = 0;
    for (; seg < 255; ++seg) {
      u32 ps = part[seg];
      if (cum + ps > r) break;
      cum += ps;
    }
    int b = seg * C;
    for (int i = 0; i < C; ++i) {
      u32 h = 0;
#pragma unroll
      for (int cp = 0; cp < NCOPY; ++cp) h += hist[cp * NBINS + b];
      if (cum + h > r) break;
      cum += h;
      ++b;
    }
    sel[0] = r - cum;
    u32 pfx = (FIRST ? 0u : sel[1]) | ((u32)b << SHIFT);
    sel[1] = pfx;
    if (LAST)
      sel[2] = (pfx & 0x80000000u) ? (pfx ^ 0x80000000u) : ~pfx;
  }
}

// ---------------------------------------------------------------------------
// Threshold + 7x7 max-pool NMS from materialized R (plan A).
// float4 staging: rows r0..r0+37, cols c0-4..c0+35 (40 cols, 4-aligned).
// Needed window cols are local 1..38; cols 0,39 are alignment padding.
// ---------------------------------------------------------------------------
__global__ __launch_bounds__(256) void final_pool(const float* __restrict__ R,
                                                  const u32* __restrict__ sel,
                                                  float* __restrict__ out) {
  __shared__ __align__(16) float rt[38][44];
  __shared__ float hm[38][32];
  const float med = __uint_as_float(sel[2]);
  const int r0 = blockIdx.y * TS - 3;
  const int c0 = blockIdx.x * TS;
  const int c0m4 = c0 - 4;
  // stage + threshold (float4)
  for (int idx = threadIdx.x; idx < 38 * 10; idx += 256) {
    int r = idx / 10, j = idx % 10;
    int gr = r0 + r, gc = c0m4 + 4 * j;
    float4 v4;
    float* vp = (float*)&v4;
    if ((u32)gr < (u32)HW && gc >= 0 && gc + 3 < HW) {
      float4 Rv = *(const float4*)&R[(size_t)gr * HW + gc];
      v4.x = (Rv.x > med) ? Rv.x : 0.f;
      v4.y = (Rv.y > med) ? Rv.y : 0.f;
      v4.z = (Rv.z > med) ? Rv.z : 0.f;
      v4.w = (Rv.w > med) ? Rv.w : 0.f;
    } else {
#pragma unroll
      for (int t = 0; t < 4; ++t) {
        int g2 = gc + t;
        float val = -INFINITY;
        if ((u32)gr < (u32)HW && (u32)g2 < (u32)HW) {
          float Rv = R[(size_t)gr * HW + g2];
          val = (Rv > med) ? Rv : 0.f;
        }
        vp[t] = val;
      }
    }
    *(float4*)&rt[r][4 * j] = v4;
  }
  __syncthreads();
  // horizontal 7-max: hm[r][c] = max rt[r][c+1 .. c+7]
  for (int idx = threadIdx.x; idx < 38 * TS; idx += 256) {
    int r = idx / TS, c = idx % TS;
    float m = rt[r][c + 1];
#pragma unroll
    for (int k = 2; k < 8; ++k) m = fmaxf(m, rt[r][c + k]);
    hm[r][c] = m;
  }
  __syncthreads();
  // vertical 7-max + NMS mask
  for (int idx = threadIdx.x; idx < TS * TS; idx += 256) {
    int r = idx / TS, c = idx % TS;
    float pooled = hm[r][c];
#pragma unroll
    for (int k = 1; k < 7; ++k) pooled = fmaxf(pooled, hm[r + k][c]);
    float rc = rt[r + 3][c + 4];
    out[(size_t)(r0 + 3 + r) * HW + (c0 + c)] = (rc == pooled) ? rc : 0.f;
  }
}

// ---------------------------------------------------------------------------
extern "C" void kernel_launch(void* const* d_in, const int* in_sizes, int n_in,
                              void* d_out, int out_size, void* d_ws,
                              size_t ws_size, hipStream_t stream) {
  (void)in_sizes;
  (void)n_in;
  (void)out_size;
  const float* x = (const float*)d_in[0];
  const float* gw = (const float*)d_in[2];  // d_in[1] (sobel weights) baked in
  float* out = (float*)d_out;

  const size_t RB = (size_t)NPIX * sizeof(float);
  // h1: 16x1024, h2: 4x4096, h3: 4x1024, sel: 8
  const size_t HN = H1_COPIES * 1024 + H23_COPIES * 4096 + H23_COPIES * 1024 + 8;
  const size_t HB = HN * sizeof(u32);  // ~147 KB
  const bool planA = ws_size >= RB + HB;

  float* Rbuf;
  u32* hb;
  if (planA) {
    Rbuf = (float*)d_ws;
    hb = (u32*)((char*)d_ws + RB);
  } else {
    Rbuf = out;  // fallback: R staged in d_out; final pass recomputes per-tile
    hb = (u32*)d_ws;
  }
  u32* h1 = hb;
  u32* h2 = h1 + H1_COPIES * 1024;
  u32* h3 = h2 + H23_COPIES * 4096;
  u32* sel = h3 + H23_COPIES * 1024;

  dim3 grid(HW / TS, HW / TS);
  hipMemsetAsync(hb, 0, HB, stream);
  harris_main<32, false><<<grid, 256, 0, stream>>>(x, gw, nullptr, Rbuf, h1);
  scan_select<1024, H1_COPIES, 22, true, false><<<1, 256, 0, stream>>>(h1, sel);
  hist_pass2<<<1024, 256, 0, stream>>>((const float4*)Rbuf, sel, h2);
  scan_select<4096, H23_COPIES, 10, false, false><<<1, 256, 0, stream>>>(h2,
                                                                         sel);
  hist_pass3<<<1024, 256, 0, stream>>>((const float4*)Rbuf, sel, h3);
  scan_select<1024, H23_COPIES, 0, false, true><<<1, 256, 0, stream>>>(h3, sel);
  if (planA) {
    final_pool<<<grid, 256, 0, stream>>>(Rbuf, sel, out);
  } else {
    harris_main<38, true><<<grid, 256, 0, stream>>>(x, gw, sel, out, nullptr);
  }
}